// Round 6
// baseline (337.791 us; speedup 1.0000x reference)
//
#include <hip/hip_runtime.h>

// fg/bg masked unbiased variance, Pred/GT fp32 [4096,1,100,100].
// One-pass var: var = (sumsq - n*mean^2)/(n-1)  (exact rewrite of reference).
// Round 6: STREAM-SPLIT probe. R1/R2/R5 (block-per-sample, deep-unroll,
// wave-per-sample) all plateau at 117.5us / 2.79 TB/s effective read ->
// drain-rate limited, not concurrency limited. Unknown: paired-stream
// penalty vs ~3 TB/s read-path ceiling. This round decouples:
//   K1: read GT only (L3-hot from harness restore) -> 2-bit/elem mask (10.24 MB)
//   K2: read Pred (single HBM stream) + mask -> per-sample count/sum/sumsq
// Same predicates, same per-lane accumulation order -> bit-identical result.
// Fallback to the round-5 fused kernel if ws_size < mask requirement.

#define NSAMP   4096
#define ELEMS   10000                 // 100*100 per sample
#define VECS    (ELEMS / 4)           // 2500 float4 per sample
#define TOTVEC  (NSAMP * VECS)        // 10,240,000 float4s total
#define BLOCK   256

// K1 geometry: 2500 blocks x 256 threads x 16 vec4s, contiguous 64 KB slabs
#define K1_SLAB 4096                  // vec4s per block
#define K1_NB   (TOTVEC / K1_SLAB)    // 2500
#define K1_VPT  (K1_SLAB / BLOCK)     // 16

// K2 geometry: wave-per-sample (round-5 structure)
#define WPB     4
#define NBLK    (NSAMP / WPB)         // 1024
#define RPG     3
#define GROUPS  13                    // 13*3*64 = 2496 vec4s
#define TAILV   (VECS - GROUPS * RPG * 64)  // 4 (lanes 0..3)

#define MASK_OFF (64 * 1024)          // vars live in [0, 32KB); mask at 64KB

// ---------------- K1: GT -> packed 2-bit mask (1 byte per float4) ----------
__global__ __launch_bounds__(BLOCK) void mask_build(
        const float* __restrict__ GT,
        unsigned char* __restrict__ mask) {
    const int b   = blockIdx.x;
    const int tid = threadIdx.x;
    const float4* __restrict__ g4 = (const float4*)GT + (size_t)b * K1_SLAB;
    unsigned char* __restrict__ mb = mask + (size_t)b * K1_SLAB;

    float4 g[K1_VPT];
    #pragma unroll
    for (int k = 0; k < K1_VPT; ++k)
        g[k] = g4[k * BLOCK + tid];

    #pragma unroll
    for (int k = 0; k < K1_VPT; ++k) {
        unsigned int byte = 0;
        #pragma unroll
        for (int c = 0; c < 4; ++c) {
            float gg = (&g[k].x)[c];
            byte |= (gg > 0.5f ? 1u : 0u) << (2 * c);
            byte |= (gg < 0.5f ? 1u : 0u) << (2 * c + 1);
        }
        mb[k * BLOCK + tid] = (unsigned char)byte;
    }
}

// ---------------- K2: Pred + mask -> per-sample variance -------------------
__device__ __forceinline__ void consume_m(float4 p, unsigned int m,
        float& cfg, float& sfg, float& qfg,
        float& cbg, float& sbg, float& qbg) {
    #pragma unroll
    for (int c = 0; c < 4; ++c) {
        float pp = (&p.x)[c];
        float sq = pp * pp;
        bool  nz = (pp != 0.0f);
        float fg = ((((m >> (2 * c    )) & 1u) != 0u) && nz) ? 1.0f : 0.0f;
        float bg = ((((m >> (2 * c + 1)) & 1u) != 0u) && nz) ? 1.0f : 0.0f;
        cfg += fg;  sfg += fg * pp;  qfg += fg * sq;
        cbg += bg;  sbg += bg * pp;  qbg += bg * sq;
    }
}

__global__ __launch_bounds__(BLOCK) void stage1_masked(
        const float* __restrict__ Pred,
        const unsigned char* __restrict__ mask,
        float* __restrict__ vars /* [2][NSAMP]: fg then bg */) {
    const int tid  = threadIdx.x;
    const int lane = tid & 63;
    const int wid  = tid >> 6;
    const int s    = blockIdx.x * WPB + wid;

    const float4* __restrict__ p4 = (const float4*)(Pred + (size_t)s * ELEMS);
    const unsigned char* __restrict__ mr = mask + (size_t)s * VECS;

    float cfg = 0.f, sfg = 0.f, qfg = 0.f;
    float cbg = 0.f, sbg = 0.f, qbg = 0.f;

    float4       bp[2][RPG];
    unsigned int bm[2][RPG];

    #pragma unroll
    for (int r = 0; r < RPG; ++r) {
        bp[0][r] = p4[r * 64 + lane];
        bm[0][r] = mr[r * 64 + lane];
    }

    #pragma unroll
    for (int g = 0; g < GROUPS; ++g) {
        const int cur = g & 1, nxt = cur ^ 1;
        if (g + 1 < GROUPS) {
            #pragma unroll
            for (int r = 0; r < RPG; ++r) {
                const int rr = (g + 1) * RPG + r;
                bp[nxt][r] = p4[rr * 64 + lane];
                bm[nxt][r] = mr[rr * 64 + lane];
            }
        }
        #pragma unroll
        for (int r = 0; r < RPG; ++r)
            consume_m(bp[cur][r], bm[cur][r], cfg, sfg, qfg, cbg, sbg, qbg);
    }

    if (lane < TAILV) {
        float4       p = p4[GROUPS * RPG * 64 + lane];
        unsigned int m = mr[GROUPS * RPG * 64 + lane];
        consume_m(p, m, cfg, sfg, qfg, cbg, sbg, qbg);
    }

    float vals[6] = {cfg, sfg, qfg, cbg, sbg, qbg};
    #pragma unroll
    for (int k = 0; k < 6; ++k) {
        float v = vals[k];
        #pragma unroll
        for (int off = 32; off > 0; off >>= 1)
            v += __shfl_down(v, off, 64);
        vals[k] = v;
    }

    if (lane == 0) {
        {
            float n    = vals[0];
            float mean = vals[1] / n;
            vars[s] = (vals[2] - n * mean * mean) / (n - 1.0f);
        }
        {
            float n    = vals[3];
            float mean = vals[4] / n;
            vars[NSAMP + s] = (vals[5] - n * mean * mean) / (n - 1.0f);
        }
    }
}

// ---------------- Fallback (round-5 fused) --------------------------------
__device__ __forceinline__ void consume(float4 p, float4 g,
        float& cfg, float& sfg, float& qfg,
        float& cbg, float& sbg, float& qbg) {
    #pragma unroll
    for (int c = 0; c < 4; ++c) {
        float pp = (&p.x)[c];
        float gg = (&g.x)[c];
        float sq = pp * pp;
        bool  nz = (pp != 0.0f);
        float fg = (gg > 0.5f && nz) ? 1.0f : 0.0f;
        float bg = (gg < 0.5f && nz) ? 1.0f : 0.0f;
        cfg += fg;  sfg += fg * pp;  qfg += fg * sq;
        cbg += bg;  sbg += bg * pp;  qbg += bg * sq;
    }
}

__global__ __launch_bounds__(BLOCK) void stage1_wave_per_sample(
        const float* __restrict__ Pred,
        const float* __restrict__ GT,
        float* __restrict__ vars) {
    const int tid  = threadIdx.x;
    const int lane = tid & 63;
    const int wid  = tid >> 6;
    const int s    = blockIdx.x * WPB + wid;

    const float4* __restrict__ p4 = (const float4*)(Pred + (size_t)s * ELEMS);
    const float4* __restrict__ g4 = (const float4*)(GT   + (size_t)s * ELEMS);

    float cfg = 0.f, sfg = 0.f, qfg = 0.f;
    float cbg = 0.f, sbg = 0.f, qbg = 0.f;

    float4 bp[2][RPG], bg_[2][RPG];
    #pragma unroll
    for (int r = 0; r < RPG; ++r) {
        bp [0][r] = p4[r * 64 + lane];
        bg_[0][r] = g4[r * 64 + lane];
    }
    #pragma unroll
    for (int g = 0; g < GROUPS; ++g) {
        const int cur = g & 1, nxt = cur ^ 1;
        if (g + 1 < GROUPS) {
            #pragma unroll
            for (int r = 0; r < RPG; ++r) {
                const int rr = (g + 1) * RPG + r;
                bp [nxt][r] = p4[rr * 64 + lane];
                bg_[nxt][r] = g4[rr * 64 + lane];
            }
        }
        #pragma unroll
        for (int r = 0; r < RPG; ++r)
            consume(bp[cur][r], bg_[cur][r], cfg, sfg, qfg, cbg, sbg, qbg);
    }
    if (lane < TAILV) {
        float4 p = p4[GROUPS * RPG * 64 + lane];
        float4 g = g4[GROUPS * RPG * 64 + lane];
        consume(p, g, cfg, sfg, qfg, cbg, sbg, qbg);
    }

    float vals[6] = {cfg, sfg, qfg, cbg, sbg, qbg};
    #pragma unroll
    for (int k = 0; k < 6; ++k) {
        float v = vals[k];
        #pragma unroll
        for (int off = 32; off > 0; off >>= 1)
            v += __shfl_down(v, off, 64);
        vals[k] = v;
    }
    if (lane == 0) {
        {
            float n    = vals[0];
            float mean = vals[1] / n;
            vars[s] = (vals[2] - n * mean * mean) / (n - 1.0f);
        }
        {
            float n    = vals[3];
            float mean = vals[4] / n;
            vars[NSAMP + s] = (vals[5] - n * mean * mean) / (n - 1.0f);
        }
    }
}

// ---------------- stage 2 --------------------------------------------------
__global__ __launch_bounds__(BLOCK) void stage2_mean(
        const float* __restrict__ vars,
        float* __restrict__ out) {
    const int tid = threadIdx.x;
    float sf = 0.f, sb = 0.f;
    for (int i = tid; i < NSAMP; i += BLOCK) {
        sf += vars[i];
        sb += vars[NSAMP + i];
    }
    const int lane = tid & 63;
    const int wid  = tid >> 6;
    __shared__ float red[2][BLOCK / 64];
    float rf = sf, rb = sb;
    #pragma unroll
    for (int off = 32; off > 0; off >>= 1) {
        rf += __shfl_down(rf, off, 64);
        rb += __shfl_down(rb, off, 64);
    }
    if (lane == 0) { red[0][wid] = rf; red[1][wid] = rb; }
    __syncthreads();
    if (tid == 0) {
        float a = 0.f, b2 = 0.f;
        #pragma unroll
        for (int w = 0; w < BLOCK / 64; ++w) { a += red[0][w]; b2 += red[1][w]; }
        out[0] = a  / (float)NSAMP;  // fg_var
        out[1] = b2 / (float)NSAMP;  // bg_var
    }
}

extern "C" void kernel_launch(void* const* d_in, const int* in_sizes, int n_in,
                              void* d_out, int out_size, void* d_ws, size_t ws_size,
                              hipStream_t stream) {
    const float* Pred = (const float*)d_in[0];
    const float* GT   = (const float*)d_in[1];
    float* out  = (float*)d_out;
    float* vars = (float*)d_ws;                                  // 32 KB
    unsigned char* mask = (unsigned char*)d_ws + MASK_OFF;       // 10.24 MB

    const bool split = ws_size >= (size_t)MASK_OFF + (size_t)TOTVEC;

    if (split) {
        mask_build<<<K1_NB, BLOCK, 0, stream>>>(GT, mask);
        stage1_masked<<<NBLK, BLOCK, 0, stream>>>(Pred, mask, vars);
    } else {
        stage1_wave_per_sample<<<NBLK, BLOCK, 0, stream>>>(Pred, GT, vars);
    }
    stage2_mean<<<1, BLOCK, 0, stream>>>(vars, out);
}

// Round 8
// 332.834 us; speedup vs baseline: 1.0149x; 1.0149x over previous
//
#include <hip/hip_runtime.h>

// fg/bg masked unbiased variance, Pred/GT fp32 [4096,1,100,100].
// One-pass var: var = (sumsq - n*mean^2)/(n-1)  (exact rewrite of reference).
// Round 8 = round 7 resubmit (bench infra timeout, experiment never ran):
// INLINE-ASM READ PIPELINE. R1-R6 all plateau at ~2.8 TB/s read; writes
// (harness poison fill) hit 6.87 TB/s on the same machine. Compiler
// re-serialized every source-level prefetch (VGPR 48/48/44). This round
// forces 12 global_load_dwordx4 in flight per wave via asm volatile issue +
// counted s_waitcnt vmcnt(N) + sched_barrier(0) (HK T3/T4 pattern, rule #18).
// Per-lane consumption order identical to R5 -> bit-identical output.

#define NSAMP   4096
#define ELEMS   10000          // 100*100 per sample
#define VECS    (ELEMS / 4)    // 2500 float4 per sample
#define BLOCK   256
#define WPB     4              // waves per block
#define NBLK    (NSAMP / WPB)  // 1024
#define RPG     3              // rounds (64 lanes) per group -> 6 loads/group
#define NGRP    13             // 13*3*64 = 2496 vec4s
#define TAILV   (VECS - NGRP * RPG * 64)   // 4 (lanes 0..3)

__device__ __forceinline__ void consume(float4 p, float4 g,
        float& cfg, float& sfg, float& qfg,
        float& cbg, float& sbg, float& qbg) {
    #pragma unroll
    for (int c = 0; c < 4; ++c) {
        float pp = (&p.x)[c];
        float gg = (&g.x)[c];
        float sq = pp * pp;
        bool  nz = (pp != 0.0f);
        float fg = (gg > 0.5f && nz) ? 1.0f : 0.0f;
        float bg = (gg < 0.5f && nz) ? 1.0f : 0.0f;
        cfg += fg;  sfg += fg * pp;  qfg += fg * sq;
        cbg += bg;  sbg += bg * pp;  qbg += bg * sq;
    }
}

// Issue one group (3 Pred + 3 GT dwordx4 loads) into buffer slot S.
// asm volatile: ordered among themselves, cannot be sunk by the scheduler.
#define ISSUE(S, G) do {                                                     \
    asm volatile("global_load_dwordx4 %0, %1, off"                           \
                 : "=v"(bp[S][0]) : "v"(pb + ((G)*RPG + 0) * 1024));         \
    asm volatile("global_load_dwordx4 %0, %1, off"                           \
                 : "=v"(bgr[S][0]) : "v"(gb + ((G)*RPG + 0) * 1024));        \
    asm volatile("global_load_dwordx4 %0, %1, off"                           \
                 : "=v"(bp[S][1]) : "v"(pb + ((G)*RPG + 1) * 1024));         \
    asm volatile("global_load_dwordx4 %0, %1, off"                           \
                 : "=v"(bgr[S][1]) : "v"(gb + ((G)*RPG + 1) * 1024));        \
    asm volatile("global_load_dwordx4 %0, %1, off"                           \
                 : "=v"(bp[S][2]) : "v"(pb + ((G)*RPG + 2) * 1024));         \
    asm volatile("global_load_dwordx4 %0, %1, off"                           \
                 : "=v"(bgr[S][2]) : "v"(gb + ((G)*RPG + 2) * 1024));        \
} while (0)

__global__ __launch_bounds__(BLOCK, 1) void stage1_asm_pipe(
        const float* __restrict__ Pred,
        const float* __restrict__ GT,
        float* __restrict__ vars /* [2][NSAMP]: fg then bg */) {
    const int tid  = threadIdx.x;
    const int lane = tid & 63;
    const int wid  = tid >> 6;
    const int s    = blockIdx.x * WPB + wid;   // sample owned by this wave

    const char* pb = (const char*)(Pred + (size_t)s * ELEMS) + (size_t)lane * 16;
    const char* gb = (const char*)(GT   + (size_t)s * ELEMS) + (size_t)lane * 16;
    const float4* __restrict__ p4 = (const float4*)(Pred + (size_t)s * ELEMS);
    const float4* __restrict__ g4 = (const float4*)(GT   + (size_t)s * ELEMS);

    float cfg = 0.f, sfg = 0.f, qfg = 0.f;
    float cbg = 0.f, sbg = 0.f, qbg = 0.f;

    // Tail loads FIRST (plain C): they can only land in the prologue region
    // (cannot sink past the first "memory"-clobber waitcnt asm), where extra
    // OLDER outstanding loads only strengthen the counted waits.
    float4 tp = {0, 0, 0, 0}, tg = {0, 0, 0, 0};
    const bool has_tail = (lane < TAILV);
    if (has_tail) {
        tp = p4[NGRP * RPG * 64 + lane];
        tg = g4[NGRP * RPG * 64 + lane];
    }

    // 3 rotating buffer slots; all indices compile-time after full unroll.
    float4 bp[3][RPG], bgr[3][RPG];

    ISSUE(0, 0);
    ISSUE(1, 1);

    #pragma unroll
    for (int t = 0; t < NGRP; ++t) {
        // Counted wait: groups t,t+1 (12 loads) outstanding in steady state;
        // vmcnt(6) -> the oldest 6 (= group t) have landed.
        if (t <= NGRP - 2) asm volatile("s_waitcnt vmcnt(6)" ::: "memory");
        else               asm volatile("s_waitcnt vmcnt(0)" ::: "memory");
        __builtin_amdgcn_sched_barrier(0);   // rule #18: pin consumes below

        if (t + 2 <= NGRP - 1) {
            const int ns = (t + 2) % 3;
            if      (ns == 0) ISSUE(0, t + 2);
            else if (ns == 1) ISSUE(1, t + 2);
            else              ISSUE(2, t + 2);
        }

        const int cs = t % 3;
        #pragma unroll
        for (int r = 0; r < RPG; ++r) {
            if      (cs == 0) consume(bp[0][r], bgr[0][r], cfg, sfg, qfg, cbg, sbg, qbg);
            else if (cs == 1) consume(bp[1][r], bgr[1][r], cfg, sfg, qfg, cbg, sbg, qbg);
            else              consume(bp[2][r], bgr[2][r], cfg, sfg, qfg, cbg, sbg, qbg);
        }
    }

    if (has_tail)
        consume(tp, tg, cfg, sfg, qfg, cbg, sbg, qbg);

    // ---- wave-only reduction (no LDS, no barrier) ----
    float vals[6] = {cfg, sfg, qfg, cbg, sbg, qbg};
    #pragma unroll
    for (int k = 0; k < 6; ++k) {
        float v = vals[k];
        #pragma unroll
        for (int off = 32; off > 0; off >>= 1)
            v += __shfl_down(v, off, 64);
        vals[k] = v;
    }

    if (lane == 0) {
        {
            float n    = vals[0];
            float mean = vals[1] / n;
            vars[s] = (vals[2] - n * mean * mean) / (n - 1.0f);
        }
        {
            float n    = vals[3];
            float mean = vals[4] / n;
            vars[NSAMP + s] = (vals[5] - n * mean * mean) / (n - 1.0f);
        }
    }
}

__global__ __launch_bounds__(BLOCK) void stage2_mean(
        const float* __restrict__ vars,
        float* __restrict__ out) {
    const int tid = threadIdx.x;
    float sf = 0.f, sb = 0.f;
    for (int i = tid; i < NSAMP; i += BLOCK) {
        sf += vars[i];
        sb += vars[NSAMP + i];
    }
    const int lane = tid & 63;
    const int wid  = tid >> 6;
    __shared__ float red[2][BLOCK / 64];
    float rf = sf, rb = sb;
    #pragma unroll
    for (int off = 32; off > 0; off >>= 1) {
        rf += __shfl_down(rf, off, 64);
        rb += __shfl_down(rb, off, 64);
    }
    if (lane == 0) { red[0][wid] = rf; red[1][wid] = rb; }
    __syncthreads();
    if (tid == 0) {
        float a = 0.f, b2 = 0.f;
        #pragma unroll
        for (int w = 0; w < BLOCK / 64; ++w) { a += red[0][w]; b2 += red[1][w]; }
        out[0] = a  / (float)NSAMP;  // fg_var
        out[1] = b2 / (float)NSAMP;  // bg_var
    }
}

extern "C" void kernel_launch(void* const* d_in, const int* in_sizes, int n_in,
                              void* d_out, int out_size, void* d_ws, size_t ws_size,
                              hipStream_t stream) {
    const float* Pred = (const float*)d_in[0];
    const float* GT   = (const float*)d_in[1];
    float* out  = (float*)d_out;
    float* vars = (float*)d_ws;   // 2*NSAMP floats = 32 KB

    stage1_asm_pipe<<<NBLK, BLOCK, 0, stream>>>(Pred, GT, vars);
    stage2_mean<<<1, BLOCK, 0, stream>>>(vars, out);
}